// Round 7
// baseline (1001.817 us; speedup 1.0000x reference)
//
#include <hip/hip_runtime.h>
#include <hip/hip_bf16.h>
#include <stdint.h>

// Problem: T=128, B=32, D=1024, H=1024 LSTM unroll, fp32 in/out.
#define T_STEPS 128
#define BATCH   32
#define DIM     1024
#define HID     1024
#define NGATE   4096            // 4*H
#define MROWS   4096            // T*B
#define NWGR    32              // recurrence worker workgroups (one XCD)
#define NWGRID  256             // launched WGs (1 per CU; workers elected)
#define FSTRIDE 32              // u32s per flag (one 128B line each)

typedef unsigned int u32;
typedef __attribute__((ext_vector_type(8)))  __bf16 bf16x8;
typedef __attribute__((ext_vector_type(4)))  float  f32x4;
typedef __attribute__((ext_vector_type(16))) float  f32x16;
typedef __attribute__((ext_vector_type(4)))  u32    u32x4;

__device__ __forceinline__ unsigned short f2bf(float f) {
    u32 x = __float_as_uint(f);
    return (unsigned short)((x + 0x7fffu + ((x >> 16) & 1u)) >> 16);  // RNE
}
__device__ __forceinline__ float sigf(float x) {
    return 1.0f / (1.0f + __expf(-x));
}
__device__ __forceinline__ float tanh_fast(float x) {
    float ax = fabsf(x);
    float e  = __expf(-2.0f * ax);           // in (0,1], no overflow
    float t  = (1.0f - e) / (1.0f + e);
    return copysignf(t, x);
}

// ---- DEVICE-scope (sc1) load: bypasses L1 + per-XCD L2 (R5-proven).
// Used only for the one-time winner election (cross-XCD).
__device__ __forceinline__ u32 poll_load_dev(const u32* p) {
    u32 v;
    asm volatile("global_load_dword %0, %1, off sc1\n\ts_waitcnt vmcnt(0)"
                 : "=v"(v) : "v"(p) : "memory");
    return v;
}
// ---- L2-anchored atomic read: L1 has NO atomic units on CDNA, so every
// vector atomic executes at the XCD's shared L2 regardless of scope bits.
// (R6's sc0 plain loads could hit stale L1 -> infinite spin -> the hang.)
// sc0 on an atomic = return-old-value.
__device__ __forceinline__ u32 atomic_read_l2(u32* p) {
    u32 v;
    asm volatile("global_atomic_or %0, %1, %2, off sc0\n\ts_waitcnt vmcnt(0)"
                 : "=v"(v) : "v"(p), "v"(0u) : "memory");
    return v;
}
// ---- L2-executed store (return-less atomic swap).
__device__ __forceinline__ void atomic_store_l2(u32* p, u32 v) {
    asm volatile("global_atomic_swap %0, %1, off" :: "v"(p), "v"(v) : "memory");
}

// ---------------- prep kernels ----------------

__global__ void cast_f32_bf16(const float* __restrict__ in,
                              unsigned short* __restrict__ out, int n) {
    int idx = (blockIdx.x * blockDim.x + threadIdx.x) * 4;
    if (idx + 3 < n) {
        float4 v = *(const float4*)(in + idx);
        ushort4 o;
        o.x = f2bf(v.x); o.y = f2bf(v.y); o.z = f2bf(v.z); o.w = f2bf(v.w);
        *(ushort4*)(out + idx) = o;
    }
}

__global__ void zero_u32(u32* __restrict__ p, int n) {
    int i = blockIdx.x * blockDim.x + threadIdx.x;
    if (i < n) p[i] = 0u;
}

// in: R x C fp32 (row-major) -> out: C x R bf16 (row-major transpose)
__global__ void transpose_cast(const float* __restrict__ in,
                               unsigned short* __restrict__ out, int R, int C) {
    __shared__ float tile[32][33];
    int c0 = blockIdx.x * 32, r0 = blockIdx.y * 32;
    int tx = threadIdx.x, ty = threadIdx.y;     // 32 x 8
#pragma unroll
    for (int i = 0; i < 4; ++i)
        tile[ty + i * 8][tx] = in[(size_t)(r0 + ty + i * 8) * C + c0 + tx];
    __syncthreads();
#pragma unroll
    for (int i = 0; i < 4; ++i)
        out[(size_t)(c0 + ty + i * 8) * R + r0 + tx] = f2bf(tile[tx][ty + i * 8]);
}

// ---------------- phase 1: Gp = perm(x @ Wx + b)  (bf16 MFMA, fp32 out) ----------------
// A: MROWS x DIM bf16 (x), BT: NGATE x DIM bf16 (WxT).
// Output written in recurrence-friendly permuted panels:
//   orig col co = g*1024 + hu  ->  panel wg = hu>>5, local col cp = g*32 + (hu&31)
//   Gp[((wg*MROWS)+row)*128 + cp]
__global__ __launch_bounds__(256) void gemm_xw(
    const unsigned short* __restrict__ A,
    const unsigned short* __restrict__ BT,
    const float* __restrict__ bias,
    float* __restrict__ Gp) {
    __shared__ unsigned short As[128 * 32];
    __shared__ unsigned short Bs[128 * 32];
    int tid  = threadIdx.x;
    int wave = tid >> 6, lane = tid & 63;
    int q = lane >> 4, c = lane & 15;
    int wm = wave >> 1, wn = wave & 1;
    int tm = blockIdx.y * 128, tn = blockIdx.x * 128;

    f32x4 acc[4][4] = {};

    const int srow0 = tid >> 2;           // 0..63
    const int srow1 = 64 + (tid >> 2);    // 64..127
    const int scol  = (tid & 3) * 8;      // bf16 elems

    u32x4 ra0, ra1, rb0, rb1;
    ra0 = *(const u32x4*)(A  + (size_t)(tm + srow0) * DIM + scol);
    ra1 = *(const u32x4*)(A  + (size_t)(tm + srow1) * DIM + scol);
    rb0 = *(const u32x4*)(BT + (size_t)(tn + srow0) * DIM + scol);
    rb1 = *(const u32x4*)(BT + (size_t)(tn + srow1) * DIM + scol);

    for (int kk = 0; kk < 32; ++kk) {
        __syncthreads();
        *(u32x4*)(As + srow0 * 32 + scol) = ra0;
        *(u32x4*)(As + srow1 * 32 + scol) = ra1;
        *(u32x4*)(Bs + srow0 * 32 + scol) = rb0;
        *(u32x4*)(Bs + srow1 * 32 + scol) = rb1;
        __syncthreads();
        if (kk < 31) {
            int ko = (kk + 1) * 32 + scol;
            ra0 = *(const u32x4*)(A  + (size_t)(tm + srow0) * DIM + ko);
            ra1 = *(const u32x4*)(A  + (size_t)(tm + srow1) * DIM + ko);
            rb0 = *(const u32x4*)(BT + (size_t)(tn + srow0) * DIM + ko);
            rb1 = *(const u32x4*)(BT + (size_t)(tn + srow1) * DIM + ko);
        }
        bf16x8 af[4], bfv[4];
#pragma unroll
        for (int i = 0; i < 4; ++i) {
            af[i]  = *(const bf16x8*)(As + (wm * 64 + i * 16 + c) * 32 + q * 8);
            bfv[i] = *(const bf16x8*)(Bs + (wn * 64 + i * 16 + c) * 32 + q * 8);
        }
#pragma unroll
        for (int i = 0; i < 4; ++i)
#pragma unroll
            for (int j = 0; j < 4; ++j)
                acc[i][j] = __builtin_amdgcn_mfma_f32_16x16x32_bf16(
                    af[i], bfv[j], acc[i][j], 0, 0, 0);
    }
    // epilogue: C/D layout col = lane&15, row = quad*4 + reg; permuted store
#pragma unroll
    for (int j = 0; j < 4; ++j) {
        int co = tn + wn * 64 + j * 16 + c;
        float bj = bias[co];
        int g = co >> 10, hu = co & 1023;
        int wgr = hu >> 5, u = hu & 31;
        int cp = g * 32 + u;
#pragma unroll
        for (int i = 0; i < 4; ++i) {
            int row0 = tm + wm * 64 + i * 16 + q * 4;
#pragma unroll
            for (int r = 0; r < 4; ++r)
                Gp[((size_t)wgr * MROWS + row0 + r) * 128 + cp] = acc[i][j][r] + bj;
        }
    }
}

// ---------------- phase 2: persistent recurrence, single-XCD election ----------------
// Launch 256 WGs x 512 threads (exactly 1/CU: LDS ~101 KB forbids 2, so all 256
// are co-resident and each XCD hosts exactly 32). Election: each WG reads its
// physical XCD id (s_getreg HW_REG_XCC_ID, m09-verified), claims a slot in a
// per-XCD counter; the 32nd claimant of an XCD CAS-elects that XCD winner.
// Winner's 32 WGs run the recurrence (slices 0..31); everyone else exits.
// Worker sync protocol (L1-proof, XCD-L2-anchored):
//   polls  = atomic-OR-with-return (atomics ALWAYS execute at L2 -- L1 has no
//            atomic units -- so no stale-L1 spin, unlike R6's sc0 loads)
//   h-store= plain stores (CDNA L1 is write-through; vmcnt-retire => in L2)
//   flag   = return-less atomic swap after s_waitcnt vmcnt(0)
//   h-load = plain cached loads (per-step addresses are fresh -> no staleness,
//            and they hit the shared L2 where producers just wrote)
// Worker geometry (as R5): wave wv: cg = wv&1 (2x 32-col tiles), ks = wv>>1
// (K-split 256 of 1024 = producers ks*8..ks*8+7); Wh fragments in 128 VGPRs/lane;
// per-producer monotone step-tag flags, one 128B line each.
__global__ __launch_bounds__(512, 1) void lstm_rec(
    const unsigned short* __restrict__ WhT,   // NGATE x DIM bf16
    const float* __restrict__ Gp,             // permuted gates, 32 x 4096 x 128 fp32
    unsigned short* hb,                       // (T+1) x BATCH x HID bf16 (slot 0 unused)
    u32* flags,                               // NWGR flags, stride FSTRIDE u32
    u32* sync,                                // [0..7]=per-XCD counters, [8]=winner(xcc+1)
    float* __restrict__ out) {                // T x BATCH x HID fp32
    __shared__ float Gl[2][32][133];          // double-buffered G slice (pad 133)
    __shared__ float SlT[4][128][33];         // K-split partials, transposed (pad 33)
    __shared__ u32 s_ctl[2];                  // [0]=slice, [1]=run?
    const int tid = threadIdx.x;

    // ---- election ----
    if (tid == 0) {
        u32 xcc;
        asm volatile("s_getreg_b32 %0, hwreg(HW_REG_XCC_ID)" : "=s"(xcc));
        xcc &= 7u;
        u32 slice = atomicAdd(&sync[xcc], 1u);
        if (slice == 31u) atomicCAS(&sync[8], 0u, xcc + 1u);
        u32 w;
        do { w = poll_load_dev(&sync[8]); } while (w == 0u);
        s_ctl[0] = slice;
        s_ctl[1] = (w == xcc + 1u && slice < 32u) ? 1u : 0u;
    }
    __syncthreads();
    if (s_ctl[1] == 0u) return;               // loser WG: free the CU
    const int wg = (int)s_ctl[0];

    const int wv = tid >> 6, lane = tid & 63;
    const int cg = wv & 1, ks = wv >> 1;
    const int ln = lane & 31, lh = lane >> 5;

    // ---- stage B-fragments (Wh) into registers, once ----
    bf16x8 br0[16], br1[16];
    {
        const unsigned short* w0 =
            WhT + (size_t)((cg * 2 + 0) * HID + wg * 32 + ln) * DIM + ks * 256 + lh * 8;
        const unsigned short* w1 =
            WhT + (size_t)((cg * 2 + 1) * HID + wg * 32 + ln) * DIM + ks * 256 + lh * 8;
#pragma unroll
        for (int kk = 0; kk < 16; ++kk) {
            br0[kk] = *(const bf16x8*)(w0 + kk * 16);
            br1[kk] = *(const bf16x8*)(w1 + kk * 16);
        }
    }

    // ---- G slice for t=0 into Gl[0] ----
    {
        const float* p = Gp + (size_t)wg * MROWS * 128 + tid * 8;
        f32x4 a = *(const f32x4*)p, b2 = *(const f32x4*)(p + 4);
        float* d = &Gl[0][tid >> 4][(tid & 15) * 8];
#pragma unroll
        for (int i = 0; i < 4; ++i) { d[i] = a[i]; d[4 + i] = b2[i]; }
    }
    __syncthreads();

    // epilogue mapping: thread = (batch, uu); owns units 2*uu, 2*uu+1
    const int batch = tid >> 4, uu = tid & 15;
    float cs0 = 0.f, cs1 = 0.f;
    f32x4 ga = {}, gb = {};

    for (int t = 0; t < T_STEPS; ++t) {
        const int cur = t & 1;

        // ---- K-phase: ballot-structured atomic poll + h-loads + 32 MFMAs ----
        f32x16 acc0 = {}, acc1 = {};
        if (t > 0) {
            u32* fp = flags + (size_t)(ks * 8 + (lane & 7)) * FSTRIDE;
            bool ready = (lane >= 8);          // lanes 0..7 watch 8 producers
            while (__ballot(!ready) != 0ull) {
                if (!ready) ready = (atomic_read_l2(fp) >= (u32)t);
            }

            const unsigned short* hrow = hb + (size_t)t * (BATCH * HID)
                                       + (size_t)ln * HID + ks * 256 + lh * 8;
            bf16x8 ha[16];
#pragma unroll
            for (int j = 0; j < 16; ++j)       // 16 x 16B plain cached loads
                ha[j] = *(const bf16x8*)(hrow + j * 16);
#pragma unroll
            for (int jj = 0; jj < 8; ++jj) {
                acc0 = __builtin_amdgcn_mfma_f32_32x32x16_bf16(ha[2 * jj],     br0[jj * 2],     acc0, 0, 0, 0);
                acc1 = __builtin_amdgcn_mfma_f32_32x32x16_bf16(ha[2 * jj],     br1[jj * 2],     acc1, 0, 0, 0);
                acc0 = __builtin_amdgcn_mfma_f32_32x32x16_bf16(ha[2 * jj + 1], br0[jj * 2 + 1], acc0, 0, 0, 0);
                acc1 = __builtin_amdgcn_mfma_f32_32x32x16_bf16(ha[2 * jj + 1], br1[jj * 2 + 1], acc1, 0, 0, 0);
            }
        }

        // ---- K-split partials into LDS (scalar, conflict-free at pad 33) ----
        // C layout 32x32: col = lane&31, row = (reg&3) + 8*(reg>>2) + 4*(lane>>5)
#pragma unroll
        for (int rg = 0; rg < 4; ++rg)
#pragma unroll
            for (int rr = 0; rr < 4; ++rr) {
                SlT[ks][cg * 64 + ln]     [rg * 8 + lh * 4 + rr] = acc0[rg * 4 + rr];
                SlT[ks][cg * 64 + 32 + ln][rg * 8 + lh * 4 + rr] = acc1[rg * 4 + rr];
            }
        if (t > 0) {   // Gl[cur] for t==0 was pre-filled; ga/gb holds slice t
            float* d = &Gl[cur][tid >> 4][(tid & 15) * 8];
#pragma unroll
            for (int i = 0; i < 4; ++i) { d[i] = ga[i]; d[4 + i] = gb[i]; }
        }
        __syncthreads();

        // ---- epilogue: units u0 = 2*uu, u1 = 2*uu+1 of batch ----
        float gv0[4], gv1[4];
#pragma unroll
        for (int g = 0; g < 4; ++g) {
            const int c0 = g * 32 + 2 * uu, c1 = c0 + 1;
            gv0[g] = Gl[cur][batch][c0] + SlT[0][c0][batch] + SlT[1][c0][batch]
                                        + SlT[2][c0][batch] + SlT[3][c0][batch];
            gv1[g] = Gl[cur][batch][c1] + SlT[0][c1][batch] + SlT[1][c1][batch]
                                        + SlT[2][c1][batch] + SlT[3][c1][batch];
        }
        float cn0 = sigf(gv0[1]) * cs0 + sigf(gv0[0]) * tanh_fast(gv0[2]);
        float cn1 = sigf(gv1[1]) * cs1 + sigf(gv1[0]) * tanh_fast(gv1[2]);
        cs0 = cn0; cs1 = cn1;
        float hv0 = sigf(gv0[3]) * tanh_fast(cn0);
        float hv1 = sigf(gv1[3]) * tanh_fast(cn1);
        u32 packed = (u32)f2bf(hv0) | ((u32)f2bf(hv1) << 16);
        // plain store: CDNA L1 is write-through -> in shared L2 at vmcnt-retire
        *(u32*)(hb + (size_t)(t + 1) * (BATCH * HID)
                   + (size_t)batch * HID + wg * 32 + 2 * uu) = packed;

        // all h stores of every thread in L2, then L2-executed flag bump
        asm volatile("s_waitcnt vmcnt(0)" ::: "memory");
        __syncthreads();
        if (tid == 0)
            atomic_store_l2(flags + (size_t)wg * FSTRIDE, (u32)(t + 1));

        // off the critical path: G prefetch for step t+1 + out-store
        if (t + 1 < T_STEPS) {
            const float* p = Gp + ((size_t)wg * MROWS + (size_t)(t + 1) * 32) * 128 + tid * 8;
            ga = *(const f32x4*)p; gb = *(const f32x4*)(p + 4);
        }
        *(float2*)(out + ((size_t)t * BATCH + batch) * HID + wg * 32 + 2 * uu) =
            make_float2(hv0, hv1);
    }
}

// ---------------- launch ----------------

extern "C" void kernel_launch(void* const* d_in, const int* in_sizes, int n_in,
                              void* d_out, int out_size, void* d_ws, size_t ws_size,
                              hipStream_t stream) {
    const float* x  = (const float*)d_in[0];   // T*B*D
    const float* Wx = (const float*)d_in[1];   // D x 4H
    const float* Wh = (const float*)d_in[2];   // H x 4H
    const float* b  = (const float*)d_in[3];   // 4H
    float* out = (float*)d_out;

    // workspace layout (bytes)
    char* ws = (char*)d_ws;
    const size_t OFF_XBF  = 0;                       // 8 MB  (4096x1024 bf16)
    const size_t OFF_WXT  = 8ull  << 20;             // 8 MB  (4096x1024 bf16)
    const size_t OFF_WHT  = 16ull << 20;             // 8 MB  (4096x1024 bf16)
    const size_t OFF_G    = 24ull << 20;             // 64 MB (32x4096x128 fp32 permuted)
    const size_t OFF_HB   = 88ull << 20;             // 129 * 64 KB = 8.0625 MB
    const size_t OFF_FLAG = 97ull << 20;             // 32 flags x 128 B + sync area
    const size_t NSYNC    = 16;                      // [0..7] cnt, [8] winner
    const size_t NEEDED   = OFF_FLAG + ((size_t)NWGR * FSTRIDE + NSYNC) * 4;
    if (ws_size < NEEDED) return;  // loud failure (output stays poisoned)

    unsigned short* xbf = (unsigned short*)(ws + OFF_XBF);
    unsigned short* WxT = (unsigned short*)(ws + OFF_WXT);
    unsigned short* WhT = (unsigned short*)(ws + OFF_WHT);
    float*          Gp  = (float*)(ws + OFF_G);
    unsigned short* hb  = (unsigned short*)(ws + OFF_HB);
    u32*            fl  = (u32*)(ws + OFF_FLAG);
    u32*            sy  = fl + (size_t)NWGR * FSTRIDE;

    // prep
    cast_f32_bf16<<<(MROWS * DIM / 4 + 255) / 256, 256, 0, stream>>>(x, xbf, MROWS * DIM);
    int nzero = NWGR * FSTRIDE + (int)NSYNC;
    zero_u32<<<(nzero + 255) / 256, 256, 0, stream>>>(fl, nzero);
    dim3 tb(32, 8);
    transpose_cast<<<dim3(NGATE / 32, DIM / 32), tb, 0, stream>>>(Wx, WxT, DIM, NGATE);
    transpose_cast<<<dim3(NGATE / 32, HID / 32), tb, 0, stream>>>(Wh, WhT, HID, NGATE);

    // phase 1: all-timestep input GEMM (permuted output)
    gemm_xw<<<dim3(NGATE / 128, MROWS / 128), 256, 0, stream>>>(xbf, WxT, b, Gp);

    // phase 2: persistent recurrence, workers elected onto one XCD
    lstm_rec<<<NWGRID, 512, 0, stream>>>(WhT, Gp, hb, fl, sy, out);
}

// Round 8
// 985.878 us; speedup vs baseline: 1.0162x; 1.0162x over previous
//
#include <hip/hip_runtime.h>
#include <hip/hip_bf16.h>
#include <stdint.h>

// Problem: T=128, B=32, D=1024, H=1024 LSTM unroll, fp32 in/out.
#define T_STEPS 128
#define BATCH   32
#define DIM     1024
#define HID     1024
#define NGATE   4096            // 4*H
#define MROWS   4096            // T*B
#define NWGR    32              // recurrence worker workgroups (one XCD)
#define NWGRID  256             // launched WGs (1 per CU; workers elected)

typedef unsigned int u32;
typedef __attribute__((ext_vector_type(8)))  __bf16 bf16x8;
typedef __attribute__((ext_vector_type(4)))  float  f32x4;
typedef __attribute__((ext_vector_type(16))) float  f32x16;
typedef __attribute__((ext_vector_type(4)))  u32    u32x4;

__device__ __forceinline__ unsigned short f2bf(float f) {
    u32 x = __float_as_uint(f);
    return (unsigned short)((x + 0x7fffu + ((x >> 16) & 1u)) >> 16);  // RNE
}
__device__ __forceinline__ float sigf(float x) {
    return 1.0f / (1.0f + __expf(-x));
}
__device__ __forceinline__ float tanh_fast(float x) {
    float ax = fabsf(x);
    float e  = __expf(-2.0f * ax);           // in (0,1], no overflow
    float t  = (1.0f - e) / (1.0f + e);
    return copysignf(t, x);
}

// ---- DEVICE-scope (sc1) load: bypasses L1 + per-XCD L2 (R5-proven).
// Used only for the one-time winner election (cross-XCD).
__device__ __forceinline__ u32 poll_load_dev(const u32* p) {
    u32 v;
    asm volatile("global_load_dword %0, %1, off sc1\n\ts_waitcnt vmcnt(0)"
                 : "=v"(v) : "v"(p) : "memory");
    return v;
}
// ---- L2-anchored atomic read: L1 has NO atomic units on CDNA, so every
// vector atomic executes at the XCD's shared L2 (L1-proof, R7-proven).
__device__ __forceinline__ u32 atomic_read_l2(u32* p) {
    u32 v;
    asm volatile("global_atomic_or %0, %1, %2, off sc0\n\ts_waitcnt vmcnt(0)"
                 : "=v"(v) : "v"(p), "v"(0u) : "memory");
    return v;
}
// ---- L2-executed return-less add (no ack wait on the issuing wave).
__device__ __forceinline__ void atomic_add_l2(u32* p, u32 v) {
    asm volatile("global_atomic_add %0, %1, off" :: "v"(p), "v"(v) : "memory");
}

// ---------------- prep kernels ----------------

__global__ void cast_f32_bf16(const float* __restrict__ in,
                              unsigned short* __restrict__ out, int n) {
    int idx = (blockIdx.x * blockDim.x + threadIdx.x) * 4;
    if (idx + 3 < n) {
        float4 v = *(const float4*)(in + idx);
        ushort4 o;
        o.x = f2bf(v.x); o.y = f2bf(v.y); o.z = f2bf(v.z); o.w = f2bf(v.w);
        *(ushort4*)(out + idx) = o;
    }
}

__global__ void zero_u32(u32* __restrict__ p, int n) {
    int i = blockIdx.x * blockDim.x + threadIdx.x;
    if (i < n) p[i] = 0u;
}

// in: R x C fp32 (row-major) -> out: C x R bf16 (row-major transpose)
__global__ void transpose_cast(const float* __restrict__ in,
                               unsigned short* __restrict__ out, int R, int C) {
    __shared__ float tile[32][33];
    int c0 = blockIdx.x * 32, r0 = blockIdx.y * 32;
    int tx = threadIdx.x, ty = threadIdx.y;     // 32 x 8
#pragma unroll
    for (int i = 0; i < 4; ++i)
        tile[ty + i * 8][tx] = in[(size_t)(r0 + ty + i * 8) * C + c0 + tx];
    __syncthreads();
#pragma unroll
    for (int i = 0; i < 4; ++i)
        out[(size_t)(c0 + ty + i * 8) * R + r0 + tx] = f2bf(tile[tx][ty + i * 8]);
}

// ---------------- phase 1: Gp = perm(x @ Wx + b)  (bf16 MFMA, fp32 out) ----------------
// A: MROWS x DIM bf16 (x), BT: NGATE x DIM bf16 (WxT).
// Output written in recurrence-friendly permuted panels:
//   orig col co = g*1024 + hu  ->  panel wg = hu>>5, local col cp = g*32 + (hu&31)
//   Gp[((wg*MROWS)+row)*128 + cp]
__global__ __launch_bounds__(256) void gemm_xw(
    const unsigned short* __restrict__ A,
    const unsigned short* __restrict__ BT,
    const float* __restrict__ bias,
    float* __restrict__ Gp) {
    __shared__ unsigned short As[128 * 32];
    __shared__ unsigned short Bs[128 * 32];
    int tid  = threadIdx.x;
    int wave = tid >> 6, lane = tid & 63;
    int q = lane >> 4, c = lane & 15;
    int wm = wave >> 1, wn = wave & 1;
    int tm = blockIdx.y * 128, tn = blockIdx.x * 128;

    f32x4 acc[4][4] = {};

    const int srow0 = tid >> 2;           // 0..63
    const int srow1 = 64 + (tid >> 2);    // 64..127
    const int scol  = (tid & 3) * 8;      // bf16 elems

    u32x4 ra0, ra1, rb0, rb1;
    ra0 = *(const u32x4*)(A  + (size_t)(tm + srow0) * DIM + scol);
    ra1 = *(const u32x4*)(A  + (size_t)(tm + srow1) * DIM + scol);
    rb0 = *(const u32x4*)(BT + (size_t)(tn + srow0) * DIM + scol);
    rb1 = *(const u32x4*)(BT + (size_t)(tn + srow1) * DIM + scol);

    for (int kk = 0; kk < 32; ++kk) {
        __syncthreads();
        *(u32x4*)(As + srow0 * 32 + scol) = ra0;
        *(u32x4*)(As + srow1 * 32 + scol) = ra1;
        *(u32x4*)(Bs + srow0 * 32 + scol) = rb0;
        *(u32x4*)(Bs + srow1 * 32 + scol) = rb1;
        __syncthreads();
        if (kk < 31) {
            int ko = (kk + 1) * 32 + scol;
            ra0 = *(const u32x4*)(A  + (size_t)(tm + srow0) * DIM + ko);
            ra1 = *(const u32x4*)(A  + (size_t)(tm + srow1) * DIM + ko);
            rb0 = *(const u32x4*)(BT + (size_t)(tn + srow0) * DIM + ko);
            rb1 = *(const u32x4*)(BT + (size_t)(tn + srow1) * DIM + ko);
        }
        bf16x8 af[4], bfv[4];
#pragma unroll
        for (int i = 0; i < 4; ++i) {
            af[i]  = *(const bf16x8*)(As + (wm * 64 + i * 16 + c) * 32 + q * 8);
            bfv[i] = *(const bf16x8*)(Bs + (wn * 64 + i * 16 + c) * 32 + q * 8);
        }
#pragma unroll
        for (int i = 0; i < 4; ++i)
#pragma unroll
            for (int j = 0; j < 4; ++j)
                acc[i][j] = __builtin_amdgcn_mfma_f32_16x16x32_bf16(
                    af[i], bfv[j], acc[i][j], 0, 0, 0);
    }
    // epilogue: C/D layout col = lane&15, row = quad*4 + reg; permuted store
#pragma unroll
    for (int j = 0; j < 4; ++j) {
        int co = tn + wn * 64 + j * 16 + c;
        float bj = bias[co];
        int g = co >> 10, hu = co & 1023;
        int wgr = hu >> 5, u = hu & 31;
        int cp = g * 32 + u;
#pragma unroll
        for (int i = 0; i < 4; ++i) {
            int row0 = tm + wm * 64 + i * 16 + q * 4;
#pragma unroll
            for (int r = 0; r < 4; ++r)
                Gp[((size_t)wgr * MROWS + row0 + r) * 128 + cp] = acc[i][j][r] + bj;
        }
    }
}

// ---------------- phase 2: persistent recurrence, monitor-wave sync ----------------
// Election (R7-proven): 256 WGs x 512 threads, 1/CU; first XCD to collect 32
// claimants wins; its WGs take slices 0..31, everyone else exits.
// Sync protocol (R8): ONE monotone arrivals counter. Producer: h-store (plain,
// write-through L1), s_waitcnt vmcnt(0) (h in shared L2), __syncthreads, tid0
// return-less atomic_add(arrivals,1). Consumer: ONLY tid0 polls
// (atomic-or-return, L2-anchored) for arrivals >= 32*t; remaining 511 threads
// wait at __syncthreads -- a hardware barrier with ZERO memory traffic. This
// kills the 2048-agent poll storm of R2-R7, which is the hypothesis for the
// invariant ~6.8us/step stall (storm queues ahead of the producer's critical
// h-stores/acks at the coherence point).
// Worker geometry (R5/R7): wave wv: cg = wv&1 (2x 32-col tiles), ks = wv>>1
// (K-split 256 of 1024); Wh fragments in 128 VGPRs/lane for all 128 steps.
__global__ __launch_bounds__(512, 1) void lstm_rec(
    const unsigned short* __restrict__ WhT,   // NGATE x DIM bf16
    const float* __restrict__ Gp,             // permuted gates, 32 x 4096 x 128 fp32
    unsigned short* hb,                       // (T+1) x BATCH x HID bf16 (slot 0 unused)
    u32* arrivals,                            // 1 monotone counter (own 128B line)
    u32* sync,                                // [0..7]=per-XCD counters, [8]=winner(xcc+1)
    float* __restrict__ out) {                // T x BATCH x HID fp32
    __shared__ float Gl[2][32][133];          // double-buffered G slice (pad 133)
    __shared__ float SlT[4][128][33];         // K-split partials, transposed (pad 33)
    __shared__ u32 s_ctl[2];                  // [0]=slice, [1]=run?
    const int tid = threadIdx.x;

    // ---- election ----
    if (tid == 0) {
        u32 xcc;
        asm volatile("s_getreg_b32 %0, hwreg(HW_REG_XCC_ID)" : "=s"(xcc));
        xcc &= 7u;
        u32 slice = atomicAdd(&sync[xcc], 1u);
        if (slice == 31u) atomicCAS(&sync[8], 0u, xcc + 1u);
        u32 w;
        do { w = poll_load_dev(&sync[8]); } while (w == 0u);
        s_ctl[0] = slice;
        s_ctl[1] = (w == xcc + 1u && slice < 32u) ? 1u : 0u;
    }
    __syncthreads();
    if (s_ctl[1] == 0u) return;               // loser WG: free the CU
    const int wg = (int)s_ctl[0];

    const int wv = tid >> 6, lane = tid & 63;
    const int cg = wv & 1, ks = wv >> 1;
    const int ln = lane & 31, lh = lane >> 5;

    // ---- stage B-fragments (Wh) into registers, once ----
    bf16x8 br0[16], br1[16];
    {
        const unsigned short* w0 =
            WhT + (size_t)((cg * 2 + 0) * HID + wg * 32 + ln) * DIM + ks * 256 + lh * 8;
        const unsigned short* w1 =
            WhT + (size_t)((cg * 2 + 1) * HID + wg * 32 + ln) * DIM + ks * 256 + lh * 8;
#pragma unroll
        for (int kk = 0; kk < 16; ++kk) {
            br0[kk] = *(const bf16x8*)(w0 + kk * 16);
            br1[kk] = *(const bf16x8*)(w1 + kk * 16);
        }
    }

    // ---- G slice for t=0 into Gl[0] ----
    {
        const float* p = Gp + (size_t)wg * MROWS * 128 + tid * 8;
        f32x4 a = *(const f32x4*)p, b2 = *(const f32x4*)(p + 4);
        float* d = &Gl[0][tid >> 4][(tid & 15) * 8];
#pragma unroll
        for (int i = 0; i < 4; ++i) { d[i] = a[i]; d[4 + i] = b2[i]; }
    }
    __syncthreads();

    // epilogue mapping: thread = (batch, uu); owns units 2*uu, 2*uu+1
    const int batch = tid >> 4, uu = tid & 15;
    float cs0 = 0.f, cs1 = 0.f;
    f32x4 ga = {}, gb = {};

    for (int t = 0; t < T_STEPS; ++t) {
        const int cur = t & 1;

        // ---- K-phase: monitor-wave detect + h-loads + 32 MFMAs ----
        f32x16 acc0 = {}, acc1 = {};
        if (t > 0) {
            if (tid == 0) {                     // sole poller of this WG
                const u32 want = (u32)(32 * t);
                while (atomic_read_l2(arrivals) < want) {}
            }
            __syncthreads();                    // hardware wait for the other 511

            const unsigned short* hrow = hb + (size_t)t * (BATCH * HID)
                                       + (size_t)ln * HID + ks * 256 + lh * 8;
            bf16x8 ha[16];
#pragma unroll
            for (int j = 0; j < 16; ++j)       // 16 x 16B plain cached loads (L2-hot)
                ha[j] = *(const bf16x8*)(hrow + j * 16);
#pragma unroll
            for (int jj = 0; jj < 8; ++jj) {
                acc0 = __builtin_amdgcn_mfma_f32_32x32x16_bf16(ha[2 * jj],     br0[jj * 2],     acc0, 0, 0, 0);
                acc1 = __builtin_amdgcn_mfma_f32_32x32x16_bf16(ha[2 * jj],     br1[jj * 2],     acc1, 0, 0, 0);
                acc0 = __builtin_amdgcn_mfma_f32_32x32x16_bf16(ha[2 * jj + 1], br0[jj * 2 + 1], acc0, 0, 0, 0);
                acc1 = __builtin_amdgcn_mfma_f32_32x32x16_bf16(ha[2 * jj + 1], br1[jj * 2 + 1], acc1, 0, 0, 0);
            }
        }

        // ---- K-split partials into LDS (scalar, conflict-free at pad 33) ----
        // C layout 32x32: col = lane&31, row = (reg&3) + 8*(reg>>2) + 4*(lane>>5)
#pragma unroll
        for (int rg = 0; rg < 4; ++rg)
#pragma unroll
            for (int rr = 0; rr < 4; ++rr) {
                SlT[ks][cg * 64 + ln]     [rg * 8 + lh * 4 + rr] = acc0[rg * 4 + rr];
                SlT[ks][cg * 64 + 32 + ln][rg * 8 + lh * 4 + rr] = acc1[rg * 4 + rr];
            }
        if (t > 0) {   // Gl[cur] for t==0 was pre-filled; ga/gb holds slice t
            float* d = &Gl[cur][tid >> 4][(tid & 15) * 8];
#pragma unroll
            for (int i = 0; i < 4; ++i) { d[i] = ga[i]; d[4 + i] = gb[i]; }
        }
        __syncthreads();

        // ---- epilogue: units u0 = 2*uu, u1 = 2*uu+1 of batch ----
        float gv0[4], gv1[4];
#pragma unroll
        for (int g = 0; g < 4; ++g) {
            const int c0 = g * 32 + 2 * uu, c1 = c0 + 1;
            gv0[g] = Gl[cur][batch][c0] + SlT[0][c0][batch] + SlT[1][c0][batch]
                                        + SlT[2][c0][batch] + SlT[3][c0][batch];
            gv1[g] = Gl[cur][batch][c1] + SlT[0][c1][batch] + SlT[1][c1][batch]
                                        + SlT[2][c1][batch] + SlT[3][c1][batch];
        }
        float cn0 = sigf(gv0[1]) * cs0 + sigf(gv0[0]) * tanh_fast(gv0[2]);
        float cn1 = sigf(gv1[1]) * cs1 + sigf(gv1[0]) * tanh_fast(gv1[2]);
        cs0 = cn0; cs1 = cn1;
        float hv0 = sigf(gv0[3]) * tanh_fast(cn0);
        float hv1 = sigf(gv1[3]) * tanh_fast(cn1);
        u32 packed = (u32)f2bf(hv0) | ((u32)f2bf(hv1) << 16);
        // plain store: CDNA L1 is write-through -> in shared L2 at vmcnt-retire
        *(u32*)(hb + (size_t)(t + 1) * (BATCH * HID)
                   + (size_t)batch * HID + wg * 32 + 2 * uu) = packed;

        // own stores in L2 -> barrier (all 512 ack'd) -> one return-less add
        asm volatile("s_waitcnt vmcnt(0)" ::: "memory");
        __syncthreads();
        if (tid == 0) atomic_add_l2(arrivals, 1u);

        // off the critical path: G prefetch for step t+1 + out-store
        if (t + 1 < T_STEPS) {
            const float* p = Gp + ((size_t)wg * MROWS + (size_t)(t + 1) * 32) * 128 + tid * 8;
            ga = *(const f32x4*)p; gb = *(const f32x4*)(p + 4);
        }
        *(float2*)(out + ((size_t)t * BATCH + batch) * HID + wg * 32 + 2 * uu) =
            make_float2(hv0, hv1);
    }
}

// ---------------- launch ----------------

extern "C" void kernel_launch(void* const* d_in, const int* in_sizes, int n_in,
                              void* d_out, int out_size, void* d_ws, size_t ws_size,
                              hipStream_t stream) {
    const float* x  = (const float*)d_in[0];   // T*B*D
    const float* Wx = (const float*)d_in[1];   // D x 4H
    const float* Wh = (const float*)d_in[2];   // H x 4H
    const float* b  = (const float*)d_in[3];   // 4H
    float* out = (float*)d_out;

    // workspace layout (bytes)
    char* ws = (char*)d_ws;
    const size_t OFF_XBF  = 0;                       // 8 MB  (4096x1024 bf16)
    const size_t OFF_WXT  = 8ull  << 20;             // 8 MB  (4096x1024 bf16)
    const size_t OFF_WHT  = 16ull << 20;             // 8 MB  (4096x1024 bf16)
    const size_t OFF_G    = 24ull << 20;             // 64 MB (32x4096x128 fp32 permuted)
    const size_t OFF_HB   = 88ull << 20;             // 129 * 64 KB = 8.0625 MB
    const size_t OFF_FLAG = 97ull << 20;             // arrivals line + sync area
    const size_t NCTL     = 64;                      // [0]=arrivals, [32..39]=cnt, [40]=winner
    const size_t NEEDED   = OFF_FLAG + NCTL * 4;
    if (ws_size < NEEDED) return;  // loud failure (output stays poisoned)

    unsigned short* xbf = (unsigned short*)(ws + OFF_XBF);
    unsigned short* WxT = (unsigned short*)(ws + OFF_WXT);
    unsigned short* WhT = (unsigned short*)(ws + OFF_WHT);
    float*          Gp  = (float*)(ws + OFF_G);
    unsigned short* hb  = (unsigned short*)(ws + OFF_HB);
    u32*            arr = (u32*)(ws + OFF_FLAG);     // own 128B line
    u32*            sy  = arr + 32;                  // election area (next line)

    // prep
    cast_f32_bf16<<<(MROWS * DIM / 4 + 255) / 256, 256, 0, stream>>>(x, xbf, MROWS * DIM);
    zero_u32<<<1, 256, 0, stream>>>(arr, (int)NCTL);
    dim3 tb(32, 8);
    transpose_cast<<<dim3(NGATE / 32, DIM / 32), tb, 0, stream>>>(Wx, WxT, DIM, NGATE);
    transpose_cast<<<dim3(NGATE / 32, HID / 32), tb, 0, stream>>>(Wh, WhT, HID, NGATE);

    // phase 1: all-timestep input GEMM (permuted output)
    gemm_xw<<<dim3(NGATE / 128, MROWS / 128), 256, 0, stream>>>(xbf, WxT, b, Gp);

    // phase 2: persistent recurrence, workers elected onto one XCD
    lstm_rec<<<NWGRID, 512, 0, stream>>>(WhT, Gp, hb, arr, sy, out);
}